// Round 9
// baseline (126.914 us; speedup 1.0000x reference)
//
#include <hip/hip_runtime.h>
#include <hip/hip_bf16.h>

#define BATCH 64
#define IN_CH 128
#define ILEN  512
#define OLEN  505
#define OCH   128
#define KDIM  1024    // IN_CH * 8
#define BK    32      // K per chunk
#define NCHK  32      // KDIM / BK
#define NWG   (OLEN * 2)

typedef float f32x4  __attribute__((ext_vector_type(4)));
typedef short bf16x8 __attribute__((ext_vector_type(8)));

__device__ __forceinline__ short f2bf(float f) {
  union { __hip_bfloat16 h; short s; } u;
  u.h = __float2bfloat16(f);
  return u.s;
}

// Per block (l, oh): GEMM M=64(b) x N=64(o) x K=1024, BK=32, 32 chunks.
// THESIS (R8 post-mortem): all prior schedules ran at ~48% HBM duty because
// only 2 synchronized pipelines/CU -> sawtooth demand. This round: 32KB LDS
// -> 5 blocks/CU, 1010 blocks ALL resident => 4-5 desynced pipelines/CU.
// B: gload_lds 16B, depth-3 ring. A: reg->bf16 LDS, 2-deep.
// vmcnt accounting, iter kc (issue order):
//   entering: B2(kc+1)+A8(kc+1) = 10 outstanding
//   issue B2(kc+2)->12, A8(kc+2)->20
//   writeA(kc+1): implicit wait A8(kc+1) -> 12 left
//   explicit vmcnt(10): retires B2(kc+1); B2(kc+2)+A8(kc+2)=10 fly across barrier
template <bool USE_TMP>
__global__ __launch_bounds__(256, 5) void lc1d_main(
    const float* __restrict__ x, const float* __restrict__ w,
    const float* __restrict__ bias, float* __restrict__ outp) {
  // bijective XCD swizzle (1010 % 8 = 2)
  const int orig = blockIdx.x;
  const int xcd = orig & 7, idx = orig >> 3;
  const int q = NWG / 8, rm = NWG % 8;
  const int wg = (xcd < rm ? xcd * (q + 1) : rm * (q + 1) + (xcd - rm) * q) + idx;
  const int l  = wg >> 1;
  const int oh = wg & 1;

  const int tid  = threadIdx.x;
  const int lane = tid & 63;
  const int wn   = tid >> 6;        // wave 0..3 -> o 16-slice
  const int r    = lane & 15;
  const int h    = lane >> 4;

  __shared__ float Bs[3][BK * 64];  // 24 KB: row ob = 32 floats(128B), chunk c'=c^(ob&7)
  __shared__ short As[2][BATCH * BK]; // 8 KB: row b = 32 shorts(64B), chunk c'=c^sA(b)

  f32x4 acc[4];
#pragma unroll
  for (int m = 0; m < 4; ++m) acc[m] = (f32x4){0.f, 0.f, 0.f, 0.f};

  const float* __restrict__ wo =
      w + (size_t)l * (OCH * KDIM) + (size_t)oh * 64 * KDIM;

  // ---- B staging map: thread tid writes Bs byte tid*16 (+it*4096) ----
  const int sob = tid >> 3;          // row ob within half (it*32 + tid>>3; it=0,1)
  const int scp = tid & 7;           // dest chunk c'
  // ---- A staging map: thread -> (il,kof) in 0..31, b = it*8 + tb ----
  const int il  = (tid & 31) >> 3;   // 0..3
  const int kof = tid & 7;
  const int tb  = tid >> 5;          // 0..7

  float aa0[8], aa1[8];              // chunk-parity A staging

  auto loadA = [&](float (&aa)[8], int kc) {
    const float* xb = x + (size_t)(kc * 4 + il) * ILEN + l + kof;
#pragma unroll
    for (int it = 0; it < 8; ++it)
      aa[it] = xb[(size_t)(it * 8 + tb) * (IN_CH * ILEN)];
  };
  auto writeA = [&](const float (&aa)[8], int buf) {
#pragma unroll
    for (int it = 0; it < 8; ++it) {
      const int b  = it * 8 + tb;
      const int sA = (b ^ (b >> 2)) & 3;
      As[buf][b * 32 + ((il ^ sA) << 3) + kof] = f2bf(aa[it]);
    }
  };
  auto stageB = [&](int buf, int kc) {
#pragma unroll
    for (int it = 0; it < 2; ++it) {
      const int ob = it * 32 + sob;
      const int c  = scp ^ (ob & 7);           // pre-swizzled source chunk
      const float* src = wo + (size_t)ob * KDIM + kc * BK + c * 4;
      __builtin_amdgcn_global_load_lds(
          (const __attribute__((address_space(1))) void*)src,
          (__attribute__((address_space(3))) void*)&Bs[buf][ob * 32 + scp * 4],
          16, 0, 0);
    }
  };

  auto compute = [&](int bufB, int bufA) {
    const int ob  = wn * 16 + r;
    const int swb = ob & 7;
    const f32x4 blo = *reinterpret_cast<const f32x4*>(
        &Bs[bufB][ob * 32 + (((2 * h) ^ swb) << 2)]);
    const f32x4 bhi = *reinterpret_cast<const f32x4*>(
        &Bs[bufB][ob * 32 + (((2 * h + 1) ^ swb) << 2)]);
    bf16x8 bfr;
#pragma unroll
    for (int j = 0; j < 4; ++j) {
      bfr[j]     = f2bf(blo[j]);
      bfr[4 + j] = f2bf(bhi[j]);
    }
#pragma unroll
    for (int mt = 0; mt < 4; ++mt) {
      const int b  = mt * 16 + r;
      const int sA = (b ^ (b >> 2)) & 3;
      const bf16x8 afr = *reinterpret_cast<const bf16x8*>(
          &As[bufA][b * 32 + ((h ^ sA) << 3)]);
      acc[mt] = __builtin_amdgcn_mfma_f32_16x16x32_bf16(afr, bfr, acc[mt], 0, 0, 0);
    }
  };

  // ---- prologue: Bs[0],As[0] ready; B(1) flying; chunk1 in aa1 ----
  loadA(aa0, 0);                                   // A8(0)
  stageB(0, 0);                                    // B2(0)
  writeA(aa0, 0);                                  // waits A8(0) -> 2 left
  loadA(aa1, 1);                                   // -> 10
  stageB(1, 1);                                    // -> 12
  asm volatile("s_waitcnt vmcnt(10) lgkmcnt(0)" ::: "memory");  // B2(0) done
  __builtin_amdgcn_sched_barrier(0);
  __builtin_amdgcn_s_barrier();
  __builtin_amdgcn_sched_barrier(0);

  auto step = [&](int kc, float (&aaW)[8], float (&aaL)[8]) {
    if (kc + 2 < NCHK) {
      stageB((kc + 2) % 3, kc + 2);
      loadA(aaL, kc + 2);
    }
    __builtin_amdgcn_sched_barrier(0);
    compute(kc % 3, kc & 1);
    if (kc + 1 < NCHK) {
      writeA(aaW, (kc + 1) & 1);    // implicit wait A8(kc+1)
      if (kc + 2 < NCHK) {
        asm volatile("s_waitcnt vmcnt(10) lgkmcnt(0)" ::: "memory");
      } else {
        asm volatile("s_waitcnt vmcnt(0) lgkmcnt(0)" ::: "memory");
      }
      __builtin_amdgcn_sched_barrier(0);
      __builtin_amdgcn_s_barrier();
      __builtin_amdgcn_sched_barrier(0);
    }
  };

  for (int kc = 0; kc < NCHK; kc += 2) {
    step(kc, aa1, aa0);        // even: write chunk kc+1 (aa1), load kc+2 -> aa0
    step(kc + 1, aa0, aa1);    // odd : write chunk kc+2 (aa0), load kc+3 -> aa1
  }

  // ---- epilogue: C/D layout col(o)=lane&15, row(b)=(lane>>4)*4+j ----
  const int og = oh * 64 + wn * 16 + r;
  if (USE_TMP) {
    float* t = outp + (size_t)l * (BATCH * OCH) + og;  // tmp[l][b][o], coalesced
#pragma unroll
    for (int mt = 0; mt < 4; ++mt)
#pragma unroll
      for (int j = 0; j < 4; ++j) {
        const int b = mt * 16 + h * 4 + j;
        t[(size_t)b * OCH] = acc[mt][j];
      }
  } else {
    const float bv = bias[og * OLEN + l];
#pragma unroll
    for (int mt = 0; mt < 4; ++mt)
#pragma unroll
      for (int j = 0; j < 4; ++j) {
        const int b = mt * 16 + h * 4 + j;
        outp[(size_t)b * (OCH * OLEN) + (size_t)og * OLEN + l] = acc[mt][j] + bv;
      }
  }
}

// tmp[l][b][o] -> out[b][o][l] (+bias), 64x64 LDS tile transpose
__global__ __launch_bounds__(256) void lc1d_tr(const float* __restrict__ tmp,
                                               const float* __restrict__ bias,
                                               float* __restrict__ out) {
  const int l0  = blockIdx.x * 64;
  const int bo0 = blockIdx.y * 64;
  const int tid = threadIdx.x;
  __shared__ float t[64][65];

  const int boj = tid & 63, lq = tid >> 6;
#pragma unroll
  for (int rr = 0; rr < 16; ++rr) {
    const int li = rr * 4 + lq;
    const int l  = l0 + li;
    if (l < OLEN) t[li][boj] = tmp[(size_t)l * (BATCH * OCH) + bo0 + boj];
  }
  __syncthreads();
  const int lj = tid & 63, bq = tid >> 6;
  const int l  = l0 + lj;
#pragma unroll
  for (int rr = 0; rr < 16; ++rr) {
    const int bl = rr * 4 + bq;
    const int bo = bo0 + bl;
    if (l < OLEN) {
      const int oc = bo & (OCH - 1);
      out[(size_t)bo * OLEN + l] = t[lj][bl] + bias[oc * OLEN + l];
    }
  }
}

extern "C" void kernel_launch(void* const* d_in, const int* in_sizes, int n_in,
                              void* d_out, int out_size, void* d_ws, size_t ws_size,
                              hipStream_t stream) {
  const float* x    = (const float*)d_in[0];
  const float* w    = (const float*)d_in[1];
  const float* bias = (const float*)d_in[2];
  float* out        = (float*)d_out;

  const size_t need = (size_t)OLEN * BATCH * OCH * sizeof(float);  // 16.5 MB
  if (ws_size >= need) {
    float* tmp = (float*)d_ws;
    lc1d_main<true><<<dim3(NWG), 256, 0, stream>>>(x, w, bias, tmp);
    lc1d_tr<<<dim3(8, 128), 256, 0, stream>>>(tmp, bias, out);
  } else {
    lc1d_main<false><<<dim3(NWG), 256, 0, stream>>>(x, w, bias, out);
  }
}